// Round 3
// baseline (369.039 us; speedup 1.0000x reference)
//
#include <hip/hip_runtime.h>
#include <math.h>

// B=8, C=512, H=W=64, N=4096. All-fp32 inputs; bf16 MFMA compute internally.
typedef unsigned short u16;
typedef __attribute__((ext_vector_type(8))) short bf16x8;  // 8 bf16 = 4 VGPRs
typedef __attribute__((ext_vector_type(4))) float f32x4;

#define BATCH 8
#define CDIM 512
#define NDIM 4096
#define BK 32   // K-tile (bf16 elements); LDS rows are 64B, XOR-swizzled chunk slots

__device__ inline float bf2f(u16 u) {
    unsigned int x = ((unsigned int)u) << 16;
    return __uint_as_float(x);
}
__device__ inline u16 f2bf(float f) {  // round-to-nearest-even
    unsigned int u = __float_as_uint(f);
    unsigned int r = u + 0x7fffu + ((u >> 16) & 1u);
    return (u16)(r >> 16);
}

// async 16B/lane global->LDS DMA; LDS dest = uniform base + lane*16
#define GLOAD_LDS(g, l)                                                        \
    __builtin_amdgcn_global_load_lds(                                          \
        (const __attribute__((address_space(1))) void*)(g),                    \
        (__attribute__((address_space(3))) void*)(l), 16, 0, 0)

// ---------------------------------------------------------------------------
// Shared MFMA GEMM core: C[128x128] tile = A(rows m, k-contig) x B(rows n, k-contig)^T
// 256 threads = 4 waves in 2x2; each wave does 4x4 grid of 16x16x32 MFMAs.
// LDS layout [128][BK] with XOR bank swizzle: 16B chunk c of row r lives at
// slot c ^ ((r>>1)&3). Swizzle is applied on the DMA's global source address
// (LDS side of global_load_lds is fixed base+lane*16), and on the ds_read
// fragment offsets (loop-invariant). Quarter-wave ds_read_b128 then touches
// all 8 bank-quads with 2 lanes each -> conflict-free (2-way is free, m136).
// ---------------------------------------------------------------------------
__device__ inline void gemm_core(const u16* __restrict__ A, const u16* __restrict__ B,
                                 int lda, int ldb, int K,
                                 u16* As, u16* Bs, f32x4 (&acc)[4][4]) {
    const int t = threadIdx.x;
    const int wave = t >> 6, lane = t & 63;
    const int wm = (wave & 1) * 64, wn = (wave >> 1) * 64;
    const int lr = lane & 15, lq = lane >> 4;

    const int srow = wave * 32 + (lane >> 2);   // staging row (inst0); inst1 = +16
    const int cswz = (lane & 3) ^ ((srow >> 1) & 3);  // ((srow+16)>>1)&3 == same
    const int sk = cswz * 8;                    // swizzled source chunk (bf16 elems)
    const u16* Ap0 = A + (size_t)srow * lda + sk;
    const u16* Ap1 = Ap0 + (size_t)16 * lda;
    const u16* Bp0 = B + (size_t)srow * ldb + sk;
    const u16* Bp1 = Bp0 + (size_t)16 * ldb;
    u16* As0 = As + wave * 32 * BK;             // wave-uniform LDS bases
    u16* As1 = As0 + 16 * BK;
    u16* Bs0 = Bs + wave * 32 * BK;
    u16* Bs1 = Bs0 + 16 * BK;

    // loop-invariant swizzled fragment offsets
    int aoff[4], boff[4];
#pragma unroll
    for (int i = 0; i < 4; i++) {
        int ra = wm + i * 16 + lr;
        aoff[i] = ra * BK + (lq ^ ((ra >> 1) & 3)) * 8;
        int rb = wn + i * 16 + lr;
        boff[i] = rb * BK + (lq ^ ((rb >> 1) & 3)) * 8;
    }

    for (int k0 = 0; k0 < K; k0 += BK) {
        __syncthreads();
        GLOAD_LDS(Ap0 + k0, As0);
        GLOAD_LDS(Ap1 + k0, As1);
        GLOAD_LDS(Bp0 + k0, Bs0);
        GLOAD_LDS(Bp1 + k0, Bs1);
        __syncthreads();

        bf16x8 af[4], bfr[4];
#pragma unroll
        for (int i = 0; i < 4; i++) af[i] = *(const bf16x8*)(As + aoff[i]);
#pragma unroll
        for (int i = 0; i < 4; i++) bfr[i] = *(const bf16x8*)(Bs + boff[i]);
#pragma unroll
        for (int i = 0; i < 4; i++)
#pragma unroll
            for (int j = 0; j < 4; j++)
                acc[i][j] = __builtin_amdgcn_mfma_f32_16x16x32_bf16(af[i], bfr[j], acc[i][j], 0, 0, 0);
    }
}

// ---------------------------------------------------------------------------
// K0a: convert Wq/Wk/Wv fp32 -> bf16 into Wb[3][512][512]; blocks 0..47 also
// zero the qss/kss/rs_raw accumulators (12288 floats contiguous).
// ---------------------------------------------------------------------------
__global__ __launch_bounds__(256) void convw(const float* __restrict__ Wq,
                                             const float* __restrict__ Wk,
                                             const float* __restrict__ Wv,
                                             u16* __restrict__ Wb,
                                             float* __restrict__ zacc) {
    int i = blockIdx.x * 256 + threadIdx.x;     // < 3*2^18
    if (blockIdx.x < 48) zacc[i] = 0.f;
    int w = i >> 18;
    int j = i & 262143;
    const float* s = (w == 0) ? Wq : (w == 1) ? Wk : Wv;
    Wb[i] = f2bf(s[j]);
}

// ---------------------------------------------------------------------------
// K0b: transpose+convert x[b][c][n] fp32 -> xT[b][n][c] bf16. 64x64 tiles.
// ---------------------------------------------------------------------------
__global__ __launch_bounds__(256) void transpose_x(const float* __restrict__ x,
                                                   u16* __restrict__ xT) {
    __shared__ float tile[64][65];
    int n0 = blockIdx.x * 64, c0 = blockIdx.y * 64, b = blockIdx.z;
    int t = threadIdx.x;
    int tx = t & 63, ty = t >> 6;   // ty 0..3
    const float* xb = x + (size_t)b * CDIM * NDIM;
#pragma unroll
    for (int j = 0; j < 16; j++)
        tile[ty + j * 4][tx] = xb[(size_t)(c0 + ty + j * 4) * NDIM + n0 + tx];
    __syncthreads();
    u16* xTb = xT + (size_t)b * NDIM * CDIM;
    int r = t >> 3;          // 0..31
    int cg = (t & 7) * 8;
#pragma unroll
    for (int j = 0; j < 2; j++) {
        int rr = r + j * 32;
        u16 tmp[8];
#pragma unroll
        for (int i = 0; i < 8; i++) tmp[i] = f2bf(tile[cg + i][rr]);
        *(uint4*)(xTb + (size_t)(n0 + rr) * CDIM + c0 + cg) = *(uint4*)tmp;
    }
}

// ---------------------------------------------------------------------------
// K1: QKV GEMM. blockIdx.z = b*3+w. D[o][n] = sum_c W[o][c] * xT[n][c].
// w=0 -> Q[b][o][n] (+ sumsq atomics into qss), w=1 -> K (+ kss),
// w=2 -> VT[b][n][o] (pre-transposed for MV GEMM)
// ---------------------------------------------------------------------------
__global__ __launch_bounds__(256) void qkv_mfma(const u16* __restrict__ Wb,
                                                const u16* __restrict__ xT,
                                                u16* __restrict__ Qb, u16* __restrict__ Kb,
                                                u16* __restrict__ VT,
                                                float* __restrict__ qss,
                                                float* __restrict__ kss) {
    __shared__ __align__(16) u16 As[128 * BK];
    __shared__ __align__(16) u16 Bs[128 * BK];
    int bz = blockIdx.z;
    int b = bz / 3, w = bz % 3;
    int m0 = blockIdx.y * 128, n0 = blockIdx.x * 128;
    const u16* A = Wb + ((size_t)w << 18) + (size_t)m0 * CDIM;
    const u16* B = xT + (size_t)b * NDIM * CDIM + (size_t)n0 * CDIM;

    f32x4 acc[4][4];
#pragma unroll
    for (int i = 0; i < 4; i++)
#pragma unroll
        for (int j = 0; j < 4; j++) acc[i][j] = (f32x4){0.f, 0.f, 0.f, 0.f};

    gemm_core(A, B, CDIM, CDIM, CDIM, As, Bs, acc);

    int wave = threadIdx.x >> 6, lane = threadIdx.x & 63;
    int wm = (wave & 1) * 64, wn = (wave >> 1) * 64;
    int lr = lane & 15, lq = lane >> 4;

    if (w < 2) {
        u16* O = (w ? Kb : Qb) + (size_t)b * CDIM * NDIM;
#pragma unroll
        for (int mt = 0; mt < 4; mt++)
#pragma unroll
            for (int nt = 0; nt < 4; nt++) {
                int r0 = m0 + wm + mt * 16 + lq * 4;
                int cc = n0 + wn + nt * 16 + lr;
#pragma unroll
                for (int i = 0; i < 4; i++)
                    O[(size_t)(r0 + i) * NDIM + cc] = f2bf(acc[mt][nt][i]);
            }
        // fused row sum-of-squares (over this block's 128-col slice)
        float* ss = (w ? kss : qss) + b * CDIM;
#pragma unroll
        for (int mt = 0; mt < 4; mt++)
#pragma unroll
            for (int i = 0; i < 4; i++) {
                float s = 0.f;
#pragma unroll
                for (int nt = 0; nt < 4; nt++) {
                    float v = acc[mt][nt][i];
                    s += v * v;
                }
                s += __shfl_xor(s, 1); s += __shfl_xor(s, 2);
                s += __shfl_xor(s, 4); s += __shfl_xor(s, 8);
                if (lr == 0) atomicAdd(&ss[m0 + wm + mt * 16 + lq * 4 + i], s);
            }
    } else {
        u16* O = VT + (size_t)b * NDIM * CDIM;
#pragma unroll
        for (int mt = 0; mt < 4; mt++)
#pragma unroll
            for (int nt = 0; nt < 4; nt++) {
                int r0 = m0 + wm + mt * 16 + lq * 4;   // o, 4 consecutive
                int cc = n0 + wn + nt * 16 + lr;        // n
                ushort4 pk;
                pk.x = f2bf(acc[mt][nt][0]); pk.y = f2bf(acc[mt][nt][1]);
                pk.z = f2bf(acc[mt][nt][2]); pk.w = f2bf(acc[mt][nt][3]);
                *(ushort4*)(O + (size_t)cc * CDIM + r0) = pk;
            }
    }
}

// ---------------------------------------------------------------------------
// K3: split-K Gram GEMM (split=2). blockIdx.z = b*2 + s; K window [s*2048,+2048).
// Tpart[s][b][d][c] = partial( Q[c] . K[d] )   (raw dots; scaling deferred)
// ---------------------------------------------------------------------------
__global__ __launch_bounds__(256) void qk_part(const u16* __restrict__ Qb,
                                               const u16* __restrict__ Kb,
                                               float* __restrict__ Tpart) {
    __shared__ __align__(16) u16 As[128 * BK];
    __shared__ __align__(16) u16 Bs[128 * BK];
    int bz = blockIdx.z;
    int b = bz >> 1, s = bz & 1;
    int m0 = blockIdx.y * 128, n0 = blockIdx.x * 128;
    const u16* A = Qb + (size_t)b * CDIM * NDIM + (size_t)m0 * NDIM + s * 2048;
    const u16* B = Kb + (size_t)b * CDIM * NDIM + (size_t)n0 * NDIM + s * 2048;

    f32x4 acc[4][4];
#pragma unroll
    for (int i = 0; i < 4; i++)
#pragma unroll
        for (int j = 0; j < 4; j++) acc[i][j] = (f32x4){0.f, 0.f, 0.f, 0.f};

    gemm_core(A, B, NDIM, NDIM, 2048, As, Bs, acc);

    int wave = threadIdx.x >> 6, lane = threadIdx.x & 63;
    int wm = (wave & 1) * 64, wn = (wave >> 1) * 64;
    int lr = lane & 15, lq = lane >> 4;
    float* Tb = Tpart + ((size_t)(s * 8 + b) * CDIM) * CDIM;
#pragma unroll
    for (int mt = 0; mt < 4; mt++)
#pragma unroll
        for (int nt = 0; nt < 4; nt++) {
            int cbase = m0 + wm + mt * 16 + lq * 4;   // c, 4 consecutive
            int d = n0 + wn + nt * 16 + lr;
            float4 v;
            v.x = acc[mt][nt][0]; v.y = acc[mt][nt][1];
            v.z = acc[mt][nt][2]; v.w = acc[mt][nt][3];
            *(float4*)(Tb + (size_t)d * CDIM + cbase) = v;
        }
}

// ---------------------------------------------------------------------------
// K4: fused split-K reduce + cosine scale (rsqrt of fused sumsq) + col softmax.
// Row (b,d): v[c] = (sum_s Tpart[s]) * rsqrt(qss[c]) * rsqrt(kss[d]);
// a=1-v; m=max(a)+eps; z=1-4a/m; softmax over c. Writes Tf (aliases Tpart[0]).
// ---------------------------------------------------------------------------
__global__ __launch_bounds__(256) void softmax_col(const float* __restrict__ Tpart,
                                                   const float* __restrict__ qss,
                                                   const float* __restrict__ kss,
                                                   float* __restrict__ Tf) {
    __shared__ float red[4];
    int row = blockIdx.x;            // b*512 + d
    int b = row >> 9;
    const float* p = Tpart + (size_t)row * CDIM;
    float* o = Tf + (size_t)row * CDIM;
    int t = threadIdx.x;
    const size_t SS = (size_t)BATCH * CDIM * CDIM;   // per-split stride (floats)
    float rkd = rsqrtf(kss[row]);
    float q0 = rsqrtf(qss[(b << 9) + t]), q1 = rsqrtf(qss[(b << 9) + t + 256]);
    float v0 = (p[t] + p[t + SS]) * q0 * rkd;
    float v1 = (p[t + 256] + p[t + 256 + SS]) * q1 * rkd;
    float a0 = 1.f - v0, a1 = 1.f - v1;
    float m = fmaxf(a0, a1);
    for (int of = 32; of; of >>= 1) m = fmaxf(m, __shfl_down(m, of));
    if ((t & 63) == 0) red[t >> 6] = m;
    __syncthreads();
    m = fmaxf(fmaxf(red[0], red[1]), fmaxf(red[2], red[3])) + 1e-6f;
    __syncthreads();   // red about to be reused
    float inv = 4.f / m;   // /(m) then /0.25
    float b0 = 1.f - a0 * inv, b1 = 1.f - a1 * inv;
    float e0 = __expf(b0), e1 = __expf(b1);
    float s = e0 + e1;
    for (int of = 32; of; of >>= 1) s += __shfl_down(s, of);
    if ((t & 63) == 0) red[t >> 6] = s;
    __syncthreads();
    s = red[0] + red[1] + red[2] + red[3];
    float r = 1.f / s;
    o[t] = e0 * r;
    o[t + 256] = e1 * r;
}

// ---------------------------------------------------------------------------
// K5: rs_raw[b][c] += sum over 64-row d-chunk of Tf[b][d][c]  (atomic, d-split 8)
// ---------------------------------------------------------------------------
__global__ __launch_bounds__(256) void colsum(const float* __restrict__ T,
                                              float* __restrict__ rs_raw) {
    int b = blockIdx.x;
    int c = blockIdx.y * 256 + threadIdx.x;
    int d0 = blockIdx.z * 64;
    const float* p = T + (size_t)b * CDIM * CDIM + (size_t)d0 * CDIM + c;
    float s = 0.f;
    for (int d = 0; d < 64; d++) s += p[(size_t)d * CDIM];
    atomicAdd(&rs_raw[b * CDIM + c], s);
}

// ---------------------------------------------------------------------------
// K6a: Mb[b][c][d] = bf16( Tf[b][d][c] / (rs_raw[b][c]+eps) )  (transpose+scale)
// ---------------------------------------------------------------------------
__global__ __launch_bounds__(256) void mscale(const float* __restrict__ T,
                                              const float* __restrict__ rs_raw,
                                              u16* __restrict__ Mb) {
    __shared__ float tile[32][33];
    int b = blockIdx.z;
    int d0 = blockIdx.x * 32, c0 = blockIdx.y * 32;
    int tx = threadIdx.x, ty = threadIdx.y;
    const float* Tb = T + (size_t)b * CDIM * CDIM;
#pragma unroll
    for (int j = 0; j < 4; j++)
        tile[ty + j * 8][tx] = Tb[(size_t)(d0 + ty + j * 8) * CDIM + c0 + tx];
    __syncthreads();
    const float* rsb = rs_raw + b * CDIM;
    u16* Mbb = Mb + (size_t)b * CDIM * CDIM;
#pragma unroll
    for (int j = 0; j < 4; j++) {
        int c = c0 + ty + j * 8;
        float inv = 1.f / (rsb[c] + 1e-6f);
        Mbb[(size_t)c * CDIM + d0 + tx] = f2bf(tile[tx][ty + j * 8] * inv);
    }
}

// ---------------------------------------------------------------------------
// K6: out[b][c][n] = x + gamma * sum_d Mb[c][d] * VT[n][d]
// ---------------------------------------------------------------------------
__global__ __launch_bounds__(256) void out_mfma(const u16* __restrict__ Mb,
                                                const u16* __restrict__ VT,
                                                const float* __restrict__ x,
                                                const float* __restrict__ gamma,
                                                float* __restrict__ y) {
    __shared__ __align__(16) u16 As[128 * BK];
    __shared__ __align__(16) u16 Bs[128 * BK];
    int b = blockIdx.z;
    int m0 = blockIdx.y * 128, n0 = blockIdx.x * 128;
    const u16* A = Mb + (size_t)b * CDIM * CDIM + (size_t)m0 * CDIM;
    const u16* B = VT + (size_t)b * NDIM * CDIM + (size_t)n0 * CDIM;

    f32x4 acc[4][4];
#pragma unroll
    for (int i = 0; i < 4; i++)
#pragma unroll
        for (int j = 0; j < 4; j++) acc[i][j] = (f32x4){0.f, 0.f, 0.f, 0.f};

    gemm_core(A, B, CDIM, CDIM, CDIM, As, Bs, acc);

    int wave = threadIdx.x >> 6, lane = threadIdx.x & 63;
    int wm = (wave & 1) * 64, wn = (wave >> 1) * 64;
    int lr = lane & 15, lq = lane >> 4;
    float g = *gamma;
    const float* xb = x + (size_t)b * CDIM * NDIM;
    float* yb = y + (size_t)b * CDIM * NDIM;
#pragma unroll
    for (int mt = 0; mt < 4; mt++)
#pragma unroll
        for (int nt = 0; nt < 4; nt++) {
            int r0 = m0 + wm + mt * 16 + lq * 4;
            int cc = n0 + wn + nt * 16 + lr;
#pragma unroll
            for (int i = 0; i < 4; i++) {
                size_t idx = (size_t)(r0 + i) * NDIM + cc;
                yb[idx] = xb[idx] + g * acc[mt][nt][i];
            }
        }
}

// ---------------------------------------------------------------------------
extern "C" void kernel_launch(void* const* d_in, const int* in_sizes, int n_in,
                              void* d_out, int out_size, void* d_ws, size_t ws_size,
                              hipStream_t stream) {
    (void)in_sizes; (void)n_in; (void)out_size; (void)ws_size;
    const float* x     = (const float*)d_in[0];
    const float* Wq    = (const float*)d_in[1];
    const float* Wk    = (const float*)d_in[2];
    const float* Wv    = (const float*)d_in[3];
    const float* gamma = (const float*)d_in[4];
    float* y = (float*)d_out;

    char* ws = (char*)d_ws;
    // [0,32MB): xT (dead after qkv) -> reused as Tpart[2][8][512][512] fp32 (16MB).
    // Tf aliases Tpart[0]; Mb aliases Tpart[1] (dead after softmax_col).
    u16*   xT    = (u16*)(ws);                   // 32 MB  [B][4096][512] bf16
    float* Tpart = (float*)(ws);                 // 16 MB  [2][B][512][512] fp32 (alias)
    float* Tf    = (float*)(ws);                 //  8 MB  (alias of Tpart[0])
    u16*   Mb    = (u16*)(ws + 8388608);         //  4 MB  [B][512][512] bf16 (alias of Tpart[1])
    u16*   Wb    = (u16*)(ws + 33554432);        // 1.5 MB [3][512][512] bf16
    float* qss   = (float*)(ws + 35127296);      // 16 KB  sumsq(Q rows)
    float* kss   = (float*)(ws + 35143680);      // 16 KB  sumsq(K rows)
    float* rs_raw= (float*)(ws + 35160064);      // 16 KB  col sums of Tf
    u16*   Qb    = (u16*)(ws + 35176448);        // 32 MB  [B][512][4096] bf16
    u16*   Kb    = (u16*)(ws + 68730880);        // 32 MB
    u16*   VT    = (u16*)(ws + 102285312);       // 32 MB  [B][4096][512] bf16

    convw<<<3072, 256, 0, stream>>>(Wq, Wk, Wv, Wb, qss);  // qss/kss/rs_raw contiguous: zeroed
    transpose_x<<<dim3(64, 8, 8), 256, 0, stream>>>(x, xT);
    qkv_mfma<<<dim3(32, 4, 24), 256, 0, stream>>>(Wb, xT, Qb, Kb, VT, qss, kss);
    qk_part<<<dim3(4, 4, 16), 256, 0, stream>>>(Qb, Kb, Tpart);
    softmax_col<<<4096, 256, 0, stream>>>(Tpart, qss, kss, Tf);
    colsum<<<dim3(8, 2, 8), 256, 0, stream>>>(Tf, rs_raw);
    mscale<<<dim3(16, 16, 8), dim3(32, 8), 0, stream>>>(Tf, rs_raw, Mb);
    out_mfma<<<dim3(32, 4, 8), 256, 0, stream>>>(Mb, VT, x, gamma, y);
}

// Round 4
// 296.584 us; speedup vs baseline: 1.2443x; 1.2443x over previous
//
#include <hip/hip_runtime.h>
#include <math.h>

// B=8, C=512, H=W=64, N=4096. All-fp32 inputs; bf16 MFMA compute internally.
typedef unsigned short u16;
typedef __attribute__((ext_vector_type(8))) short bf16x8;  // 8 bf16 = 4 VGPRs
typedef __attribute__((ext_vector_type(4))) float f32x4;

#define BATCH 8
#define CDIM 512
#define NDIM 4096
#define BK 32   // K-tile (bf16 elements); LDS rows are 64B, XOR-swizzled chunk slots

__device__ inline float bf2f(u16 u) {
    unsigned int x = ((unsigned int)u) << 16;
    return __uint_as_float(x);
}
__device__ inline u16 f2bf(float f) {  // round-to-nearest-even
    unsigned int u = __float_as_uint(f);
    unsigned int r = u + 0x7fffu + ((u >> 16) & 1u);
    return (u16)(r >> 16);
}

// async 16B/lane global->LDS DMA; LDS dest = uniform base + lane*16
#define GLOAD_LDS(g, l)                                                        \
    __builtin_amdgcn_global_load_lds(                                          \
        (const __attribute__((address_space(1))) void*)(g),                    \
        (__attribute__((address_space(3))) void*)(l), 16, 0, 0)

// ---------------------------------------------------------------------------
// Shared MFMA GEMM core: C[128x128] tile = A(rows m, k-contig) x B(rows n, k-contig)^T
// 256 threads = 4 waves in 2x2; each wave does 4x4 grid of 16x16x32 MFMAs.
// LDS layout [128][BK], XOR bank swizzle: 16B chunk c of row r lives at slot
// c ^ ((r>>1)&3). Key algebra (keeps VGPRs flat — the r3 regression was the
// 128-VGPR occupancy cliff from runtime-offset arrays):
//   staging:  (srow>>1)&3 == (lane>>3)&3          -> per-lane constant
//   fragment: (ra>>1)&3   == (lr>>1)&3 (all i)    -> per-lane constant,
// so the 4 ds_read_b128 sit at immediate offsets i*1024B off ONE base.
// Quarter-wave b128 reads then hit all 8 bank-quads 2x each -> conflict-free.
// ---------------------------------------------------------------------------
__device__ inline void gemm_core(const u16* __restrict__ A, const u16* __restrict__ B,
                                 int lda, int ldb, int K,
                                 u16* As, u16* Bs, f32x4 (&acc)[4][4]) {
    const int t = threadIdx.x;
    const int wave = t >> 6, lane = t & 63;
    const int wm = (wave & 1) * 64, wn = (wave >> 1) * 64;
    const int lr = lane & 15, lq = lane >> 4;

    const int srow = wave * 32 + (lane >> 2);         // staging row (inst0); inst1 = +16
    const int sk = ((lane & 3) ^ ((lane >> 3) & 3)) * 8;  // swizzled source chunk
    const u16* Ap0 = A + (size_t)srow * lda + sk;
    const u16* Ap1 = Ap0 + (size_t)16 * lda;
    const u16* Bp0 = B + (size_t)srow * ldb + sk;
    const u16* Bp1 = Bp0 + (size_t)16 * ldb;
    u16* As0 = As + wave * 32 * BK;                   // wave-uniform LDS bases
    u16* As1 = As0 + 16 * BK;
    u16* Bs0 = Bs + wave * 32 * BK;
    u16* Bs1 = Bs0 + 16 * BK;

    // per-lane-constant swizzled fragment bases; reads at +i*16*BK (immediates)
    const int fswz = (lq ^ ((lr >> 1) & 3)) * 8;
    const u16* Af = As + (wm + lr) * BK + fswz;
    const u16* Bf = Bs + (wn + lr) * BK + fswz;

    for (int k0 = 0; k0 < K; k0 += BK) {
        __syncthreads();
        GLOAD_LDS(Ap0 + k0, As0);
        GLOAD_LDS(Ap1 + k0, As1);
        GLOAD_LDS(Bp0 + k0, Bs0);
        GLOAD_LDS(Bp1 + k0, Bs1);
        __syncthreads();

        bf16x8 af[4], bfr[4];
#pragma unroll
        for (int i = 0; i < 4; i++) af[i] = *(const bf16x8*)(Af + i * 16 * BK);
#pragma unroll
        for (int i = 0; i < 4; i++) bfr[i] = *(const bf16x8*)(Bf + i * 16 * BK);
#pragma unroll
        for (int i = 0; i < 4; i++)
#pragma unroll
            for (int j = 0; j < 4; j++)
                acc[i][j] = __builtin_amdgcn_mfma_f32_16x16x32_bf16(af[i], bfr[j], acc[i][j], 0, 0, 0);
    }
}

// ---------------------------------------------------------------------------
// K0a: convert Wq/Wk/Wv fp32 -> bf16 into Wb[3][512][512]; blocks 0..15 also
// zero rs_raw (4096 floats).
// ---------------------------------------------------------------------------
__global__ __launch_bounds__(256) void convw(const float* __restrict__ Wq,
                                             const float* __restrict__ Wk,
                                             const float* __restrict__ Wv,
                                             u16* __restrict__ Wb,
                                             float* __restrict__ zacc) {
    int i = blockIdx.x * 256 + threadIdx.x;     // < 3*2^18
    if (blockIdx.x < 16) zacc[i] = 0.f;
    int w = i >> 18;
    int j = i & 262143;
    const float* s = (w == 0) ? Wq : (w == 1) ? Wk : Wv;
    Wb[i] = f2bf(s[j]);
}

// ---------------------------------------------------------------------------
// K0b: transpose+convert x[b][c][n] fp32 -> xT[b][n][c] bf16. 64x64 tiles.
// ---------------------------------------------------------------------------
__global__ __launch_bounds__(256) void transpose_x(const float* __restrict__ x,
                                                   u16* __restrict__ xT) {
    __shared__ float tile[64][65];
    int n0 = blockIdx.x * 64, c0 = blockIdx.y * 64, b = blockIdx.z;
    int t = threadIdx.x;
    int tx = t & 63, ty = t >> 6;   // ty 0..3
    const float* xb = x + (size_t)b * CDIM * NDIM;
#pragma unroll
    for (int j = 0; j < 16; j++)
        tile[ty + j * 4][tx] = xb[(size_t)(c0 + ty + j * 4) * NDIM + n0 + tx];
    __syncthreads();
    u16* xTb = xT + (size_t)b * NDIM * CDIM;
    int r = t >> 3;          // 0..31
    int cg = (t & 7) * 8;
#pragma unroll
    for (int j = 0; j < 2; j++) {
        int rr = r + j * 32;
        u16 tmp[8];
#pragma unroll
        for (int i = 0; i < 8; i++) tmp[i] = f2bf(tile[cg + i][rr]);
        *(uint4*)(xTb + (size_t)(n0 + rr) * CDIM + c0 + cg) = *(uint4*)tmp;
    }
}

// ---------------------------------------------------------------------------
// K1: QKV GEMM. blockIdx.z = b*3+w. D[o][n] = sum_c W[o][c] * xT[n][c].
// w=0 -> Q[b][o][n], w=1 -> K[b][o][n], w=2 -> VT[b][n][o] (pre-transposed)
// ---------------------------------------------------------------------------
__global__ __launch_bounds__(256, 4) void qkv_mfma(const u16* __restrict__ Wb,
                                                   const u16* __restrict__ xT,
                                                   u16* __restrict__ Qb, u16* __restrict__ Kb,
                                                   u16* __restrict__ VT) {
    __shared__ __align__(16) u16 As[128 * BK];
    __shared__ __align__(16) u16 Bs[128 * BK];
    int bz = blockIdx.z;
    int b = bz / 3, w = bz % 3;
    int m0 = blockIdx.y * 128, n0 = blockIdx.x * 128;
    const u16* A = Wb + ((size_t)w << 18) + (size_t)m0 * CDIM;
    const u16* B = xT + (size_t)b * NDIM * CDIM + (size_t)n0 * CDIM;

    f32x4 acc[4][4];
#pragma unroll
    for (int i = 0; i < 4; i++)
#pragma unroll
        for (int j = 0; j < 4; j++) acc[i][j] = (f32x4){0.f, 0.f, 0.f, 0.f};

    gemm_core(A, B, CDIM, CDIM, CDIM, As, Bs, acc);

    int wave = threadIdx.x >> 6, lane = threadIdx.x & 63;
    int wm = (wave & 1) * 64, wn = (wave >> 1) * 64;
    int lr = lane & 15, lq = lane >> 4;

    if (w < 2) {
        u16* O = (w ? Kb : Qb) + (size_t)b * CDIM * NDIM;
#pragma unroll
        for (int mt = 0; mt < 4; mt++)
#pragma unroll
            for (int nt = 0; nt < 4; nt++) {
                int r0 = m0 + wm + mt * 16 + lq * 4;
                int cc = n0 + wn + nt * 16 + lr;
#pragma unroll
                for (int i = 0; i < 4; i++)
                    O[(size_t)(r0 + i) * NDIM + cc] = f2bf(acc[mt][nt][i]);
            }
    } else {
        u16* O = VT + (size_t)b * NDIM * CDIM;
#pragma unroll
        for (int mt = 0; mt < 4; mt++)
#pragma unroll
            for (int nt = 0; nt < 4; nt++) {
                int r0 = m0 + wm + mt * 16 + lq * 4;   // o, 4 consecutive
                int cc = n0 + wn + nt * 16 + lr;        // n
                ushort4 pk;
                pk.x = f2bf(acc[mt][nt][0]); pk.y = f2bf(acc[mt][nt][1]);
                pk.z = f2bf(acc[mt][nt][2]); pk.w = f2bf(acc[mt][nt][3]);
                *(ushort4*)(O + (size_t)cc * CDIM + r0) = pk;
            }
    }
}

// ---------------------------------------------------------------------------
// K2: 1/||row||_2 for Q and K rows (over N=4096). blockIdx.x = b*512+c, y=0:Q y=1:K
// ---------------------------------------------------------------------------
__global__ __launch_bounds__(256) void rownorm(const u16* __restrict__ Qb,
                                               const u16* __restrict__ Kb,
                                               float* __restrict__ rq, float* __restrict__ rk) {
    __shared__ float red[4];
    int row = blockIdx.x;
    const u16* p = (blockIdx.y ? Kb : Qb) + (size_t)row * NDIM;
    float s = 0.f;
    for (int base = threadIdx.x * 8; base < NDIM; base += 2048) {
        uint4 u = *(const uint4*)(p + base);
        const u16* q = (const u16*)&u;
#pragma unroll
        for (int j = 0; j < 8; j++) { float f = bf2f(q[j]); s += f * f; }
    }
    for (int o = 32; o; o >>= 1) s += __shfl_down(s, o);
    if ((threadIdx.x & 63) == 0) red[threadIdx.x >> 6] = s;
    __syncthreads();
    if (threadIdx.x == 0) {
        float tot = red[0] + red[1] + red[2] + red[3];
        (blockIdx.y ? rk : rq)[row] = 1.f / sqrtf(tot);
    }
}

// ---------------------------------------------------------------------------
// K3: split-K Gram GEMM (split=2). blockIdx.z = b*2 + s; K window [s*2048,+2048).
// Tpart[s][b][d][c] = partial( Q[c] . K[d] )   (raw dots; scaling deferred)
// ---------------------------------------------------------------------------
__global__ __launch_bounds__(256, 4) void qk_part(const u16* __restrict__ Qb,
                                                  const u16* __restrict__ Kb,
                                                  float* __restrict__ Tpart) {
    __shared__ __align__(16) u16 As[128 * BK];
    __shared__ __align__(16) u16 Bs[128 * BK];
    int bz = blockIdx.z;
    int b = bz >> 1, s = bz & 1;
    int m0 = blockIdx.y * 128, n0 = blockIdx.x * 128;
    const u16* A = Qb + (size_t)b * CDIM * NDIM + (size_t)m0 * NDIM + s * 2048;
    const u16* B = Kb + (size_t)b * CDIM * NDIM + (size_t)n0 * NDIM + s * 2048;

    f32x4 acc[4][4];
#pragma unroll
    for (int i = 0; i < 4; i++)
#pragma unroll
        for (int j = 0; j < 4; j++) acc[i][j] = (f32x4){0.f, 0.f, 0.f, 0.f};

    gemm_core(A, B, NDIM, NDIM, 2048, As, Bs, acc);

    int wave = threadIdx.x >> 6, lane = threadIdx.x & 63;
    int wm = (wave & 1) * 64, wn = (wave >> 1) * 64;
    int lr = lane & 15, lq = lane >> 4;
    float* Tb = Tpart + ((size_t)(s * 8 + b) * CDIM) * CDIM;
#pragma unroll
    for (int mt = 0; mt < 4; mt++)
#pragma unroll
        for (int nt = 0; nt < 4; nt++) {
            int cbase = m0 + wm + mt * 16 + lq * 4;   // c, 4 consecutive
            int d = n0 + wn + nt * 16 + lr;
            float4 v;
            v.x = acc[mt][nt][0]; v.y = acc[mt][nt][1];
            v.z = acc[mt][nt][2]; v.w = acc[mt][nt][3];
            *(float4*)(Tb + (size_t)d * CDIM + cbase) = v;
        }
}

// ---------------------------------------------------------------------------
// K4: fused split-K reduce + cosine scale + column softmax.
// Row (b,d): v[c] = (sum_s Tpart[s]) * rq[c]*rk[d]; a=1-v; m=max(a)+eps;
// z=1-4a/m; softmax over c. Writes Tf (aliases Tpart[0] 1:1 by row).
// ---------------------------------------------------------------------------
__global__ __launch_bounds__(256) void softmax_col(const float* __restrict__ Tpart,
                                                   const float* __restrict__ rq,
                                                   const float* __restrict__ rk,
                                                   float* __restrict__ Tf) {
    __shared__ float red[4];
    int row = blockIdx.x;            // b*512 + d
    int b = row >> 9;
    const float* p = Tpart + (size_t)row * CDIM;
    float* o = Tf + (size_t)row * CDIM;
    int t = threadIdx.x;
    const size_t SS = (size_t)BATCH * CDIM * CDIM;   // per-split stride (floats)
    float rkd = rk[row];
    float q0 = rq[(b << 9) + t], q1 = rq[(b << 9) + t + 256];
    float v0 = (p[t] + p[t + SS]) * q0 * rkd;
    float v1 = (p[t + 256] + p[t + 256 + SS]) * q1 * rkd;
    float a0 = 1.f - v0, a1 = 1.f - v1;
    float m = fmaxf(a0, a1);
    for (int of = 32; of; of >>= 1) m = fmaxf(m, __shfl_down(m, of));
    if ((t & 63) == 0) red[t >> 6] = m;
    __syncthreads();
    m = fmaxf(fmaxf(red[0], red[1]), fmaxf(red[2], red[3])) + 1e-6f;
    __syncthreads();   // red about to be reused
    float inv = 4.f / m;   // /(m) then /0.25
    float b0 = 1.f - a0 * inv, b1 = 1.f - a1 * inv;
    float e0 = __expf(b0), e1 = __expf(b1);
    float s = e0 + e1;
    for (int of = 32; of; of >>= 1) s += __shfl_down(s, of);
    if ((t & 63) == 0) red[t >> 6] = s;
    __syncthreads();
    s = red[0] + red[1] + red[2] + red[3];
    float r = 1.f / s;
    o[t] = e0 * r;
    o[t + 256] = e1 * r;
}

// ---------------------------------------------------------------------------
// K5: rs_raw[b][c] += sum over 64-row d-chunk of Tf[b][d][c]  (atomic, d-split 8)
// ---------------------------------------------------------------------------
__global__ __launch_bounds__(256) void colsum(const float* __restrict__ T,
                                              float* __restrict__ rs_raw) {
    int b = blockIdx.x;
    int c = blockIdx.y * 256 + threadIdx.x;
    int d0 = blockIdx.z * 64;
    const float* p = T + (size_t)b * CDIM * CDIM + (size_t)d0 * CDIM + c;
    float s = 0.f;
    for (int d = 0; d < 64; d++) s += p[(size_t)d * CDIM];
    atomicAdd(&rs_raw[b * CDIM + c], s);
}

// ---------------------------------------------------------------------------
// K6a: Mb[b][c][d] = bf16( Tf[b][d][c] / (rs_raw[b][c]+eps) )  (transpose+scale)
// ---------------------------------------------------------------------------
__global__ __launch_bounds__(256) void mscale(const float* __restrict__ T,
                                              const float* __restrict__ rs_raw,
                                              u16* __restrict__ Mb) {
    __shared__ float tile[32][33];
    int b = blockIdx.z;
    int d0 = blockIdx.x * 32, c0 = blockIdx.y * 32;
    int tx = threadIdx.x, ty = threadIdx.y;
    const float* Tb = T + (size_t)b * CDIM * CDIM;
#pragma unroll
    for (int j = 0; j < 4; j++)
        tile[ty + j * 8][tx] = Tb[(size_t)(d0 + ty + j * 8) * CDIM + c0 + tx];
    __syncthreads();
    const float* rsb = rs_raw + b * CDIM;
    u16* Mbb = Mb + (size_t)b * CDIM * CDIM;
#pragma unroll
    for (int j = 0; j < 4; j++) {
        int c = c0 + ty + j * 8;
        float inv = 1.f / (rsb[c] + 1e-6f);
        Mbb[(size_t)c * CDIM + d0 + tx] = f2bf(tile[tx][ty + j * 8] * inv);
    }
}

// ---------------------------------------------------------------------------
// K6: out[b][c][n] = x + gamma * sum_d Mb[c][d] * VT[n][d]
// ---------------------------------------------------------------------------
__global__ __launch_bounds__(256, 4) void out_mfma(const u16* __restrict__ Mb,
                                                   const u16* __restrict__ VT,
                                                   const float* __restrict__ x,
                                                   const float* __restrict__ gamma,
                                                   float* __restrict__ y) {
    __shared__ __align__(16) u16 As[128 * BK];
    __shared__ __align__(16) u16 Bs[128 * BK];
    int b = blockIdx.z;
    int m0 = blockIdx.y * 128, n0 = blockIdx.x * 128;
    const u16* A = Mb + (size_t)b * CDIM * CDIM + (size_t)m0 * CDIM;
    const u16* B = VT + (size_t)b * NDIM * CDIM + (size_t)n0 * CDIM;

    f32x4 acc[4][4];
#pragma unroll
    for (int i = 0; i < 4; i++)
#pragma unroll
        for (int j = 0; j < 4; j++) acc[i][j] = (f32x4){0.f, 0.f, 0.f, 0.f};

    gemm_core(A, B, CDIM, CDIM, CDIM, As, Bs, acc);

    int wave = threadIdx.x >> 6, lane = threadIdx.x & 63;
    int wm = (wave & 1) * 64, wn = (wave >> 1) * 64;
    int lr = lane & 15, lq = lane >> 4;
    float g = *gamma;
    const float* xb = x + (size_t)b * CDIM * NDIM;
    float* yb = y + (size_t)b * CDIM * NDIM;
#pragma unroll
    for (int mt = 0; mt < 4; mt++)
#pragma unroll
        for (int nt = 0; nt < 4; nt++) {
            int r0 = m0 + wm + mt * 16 + lq * 4;
            int cc = n0 + wn + nt * 16 + lr;
#pragma unroll
            for (int i = 0; i < 4; i++) {
                size_t idx = (size_t)(r0 + i) * NDIM + cc;
                yb[idx] = xb[idx] + g * acc[mt][nt][i];
            }
        }
}

// ---------------------------------------------------------------------------
extern "C" void kernel_launch(void* const* d_in, const int* in_sizes, int n_in,
                              void* d_out, int out_size, void* d_ws, size_t ws_size,
                              hipStream_t stream) {
    (void)in_sizes; (void)n_in; (void)out_size; (void)ws_size;
    const float* x     = (const float*)d_in[0];
    const float* Wq    = (const float*)d_in[1];
    const float* Wk    = (const float*)d_in[2];
    const float* Wv    = (const float*)d_in[3];
    const float* gamma = (const float*)d_in[4];
    float* y = (float*)d_out;

    char* ws = (char*)d_ws;
    // [0,32MB): xT (dead after qkv) -> reused as Tpart[2][8][512][512] fp32 (16MB).
    // Tf aliases Tpart[0]; Mb aliases Tpart[1] (dead after softmax_col).
    u16*   xT    = (u16*)(ws);                   // 32 MB  [B][4096][512] bf16
    float* Tpart = (float*)(ws);                 // 16 MB  [2][B][512][512] fp32 (alias)
    float* Tf    = (float*)(ws);                 //  8 MB  (alias of Tpart[0])
    u16*   Mb    = (u16*)(ws + 8388608);         //  4 MB  [B][512][512] bf16 (alias of Tpart[1])
    u16*   Wb    = (u16*)(ws + 33554432);        // 1.5 MB [3][512][512] bf16
    float* rq    = (float*)(ws + 35127296);      // 16 KB
    float* rk    = (float*)(ws + 35143680);      // 16 KB
    float* rs_raw= (float*)(ws + 35160064);      // 16 KB  col sums of Tf
    u16*   Qb    = (u16*)(ws + 35176448);        // 32 MB  [B][512][4096] bf16
    u16*   Kb    = (u16*)(ws + 68730880);        // 32 MB
    u16*   VT    = (u16*)(ws + 102285312);       // 32 MB  [B][4096][512] bf16

    convw<<<3072, 256, 0, stream>>>(Wq, Wk, Wv, Wb, rs_raw);
    transpose_x<<<dim3(64, 8, 8), 256, 0, stream>>>(x, xT);
    qkv_mfma<<<dim3(32, 4, 24), 256, 0, stream>>>(Wb, xT, Qb, Kb, VT);
    rownorm<<<dim3(4096, 2), 256, 0, stream>>>(Qb, Kb, rq, rk);
    qk_part<<<dim3(4, 4, 16), 256, 0, stream>>>(Qb, Kb, Tpart);
    softmax_col<<<4096, 256, 0, stream>>>(Tpart, rq, rk, Tf);
    colsum<<<dim3(8, 2, 8), 256, 0, stream>>>(Tf, rs_raw);
    mscale<<<dim3(16, 16, 8), dim3(32, 8), 0, stream>>>(Tf, rs_raw, Mb);
    out_mfma<<<dim3(32, 4, 8), 256, 0, stream>>>(Mb, VT, x, gamma, y);
}

// Round 5
// 281.848 us; speedup vs baseline: 1.3094x; 1.0523x over previous
//
#include <hip/hip_runtime.h>
#include <math.h>

// B=8, C=512, H=W=64, N=4096. All-fp32 inputs; bf16 MFMA compute internally.
// Algebraic form: M_raw = Wq (X X^T) Wk^T ; ||Q_c||^2 = diag(Wq G Wq^T).
typedef unsigned short u16;
typedef __attribute__((ext_vector_type(8))) short bf16x8;  // 8 bf16 = 4 VGPRs
typedef __attribute__((ext_vector_type(4))) float f32x4;

#define BATCH 8
#define CDIM 512
#define NDIM 4096
#define BK 32   // K-tile (bf16 elements); LDS rows are 64B, XOR-swizzled chunk slots

__device__ inline float bf2f(u16 u) {
    unsigned int x = ((unsigned int)u) << 16;
    return __uint_as_float(x);
}
__device__ inline u16 f2bf(float f) {  // round-to-nearest-even
    unsigned int u = __float_as_uint(f);
    unsigned int r = u + 0x7fffu + ((u >> 16) & 1u);
    return (u16)(r >> 16);
}

// async 16B/lane global->LDS DMA; LDS dest = uniform base + lane*16
#define GLOAD_LDS(g, l)                                                        \
    __builtin_amdgcn_global_load_lds(                                          \
        (const __attribute__((address_space(1))) void*)(g),                    \
        (__attribute__((address_space(3))) void*)(l), 16, 0, 0)

// ---------------------------------------------------------------------------
// Shared MFMA GEMM core (r4, proven): C[128x128] = A(m,k-contig) x B(n,k-contig)^T
// 256 threads = 4 waves 2x2; 4x4 grid of 16x16x32 MFMAs per wave.
// XOR bank swizzle with per-lane-constant offsets (VGPR=64, 0 conflicts):
//   staging chunk: (lane&3)^((lane>>3)&3);  fragment: lq^((lr>>1)&3).
// ---------------------------------------------------------------------------
__device__ inline void gemm_core(const u16* __restrict__ A, const u16* __restrict__ B,
                                 int lda, int ldb, int K,
                                 u16* As, u16* Bs, f32x4 (&acc)[4][4]) {
    const int t = threadIdx.x;
    const int wave = t >> 6, lane = t & 63;
    const int wm = (wave & 1) * 64, wn = (wave >> 1) * 64;
    const int lr = lane & 15, lq = lane >> 4;

    const int srow = wave * 32 + (lane >> 2);         // staging row (inst0); inst1 = +16
    const int sk = ((lane & 3) ^ ((lane >> 3) & 3)) * 8;  // swizzled source chunk
    const u16* Ap0 = A + (size_t)srow * lda + sk;
    const u16* Ap1 = Ap0 + (size_t)16 * lda;
    const u16* Bp0 = B + (size_t)srow * ldb + sk;
    const u16* Bp1 = Bp0 + (size_t)16 * ldb;
    u16* As0 = As + wave * 32 * BK;                   // wave-uniform LDS bases
    u16* As1 = As0 + 16 * BK;
    u16* Bs0 = Bs + wave * 32 * BK;
    u16* Bs1 = Bs0 + 16 * BK;

    const int fswz = (lq ^ ((lr >> 1) & 3)) * 8;
    const u16* Af = As + (wm + lr) * BK + fswz;
    const u16* Bf = Bs + (wn + lr) * BK + fswz;

    for (int k0 = 0; k0 < K; k0 += BK) {
        __syncthreads();
        GLOAD_LDS(Ap0 + k0, As0);
        GLOAD_LDS(Ap1 + k0, As1);
        GLOAD_LDS(Bp0 + k0, Bs0);
        GLOAD_LDS(Bp1 + k0, Bs1);
        __syncthreads();

        bf16x8 af[4], bfr[4];
#pragma unroll
        for (int i = 0; i < 4; i++) af[i] = *(const bf16x8*)(Af + i * 16 * BK);
#pragma unroll
        for (int i = 0; i < 4; i++) bfr[i] = *(const bf16x8*)(Bf + i * 16 * BK);
#pragma unroll
        for (int i = 0; i < 4; i++)
#pragma unroll
            for (int j = 0; j < 4; j++)
                acc[i][j] = __builtin_amdgcn_mfma_f32_16x16x32_bf16(af[i], bfr[j], acc[i][j], 0, 0, 0);
    }
}

// ---------------------------------------------------------------------------
// K0a: convert Wq/Wk/Wv fp32 -> bf16 into Wb[3][512][512]; blocks 0..15 zero rs_raw.
// ---------------------------------------------------------------------------
__global__ __launch_bounds__(256) void convw(const float* __restrict__ Wq,
                                             const float* __restrict__ Wk,
                                             const float* __restrict__ Wv,
                                             u16* __restrict__ Wb,
                                             float* __restrict__ zacc) {
    int i = blockIdx.x * 256 + threadIdx.x;     // < 3*2^18
    if (blockIdx.x < 16) zacc[i] = 0.f;
    int w = i >> 18;
    int j = i & 262143;
    const float* s = (w == 0) ? Wq : (w == 1) ? Wk : Wv;
    Wb[i] = f2bf(s[j]);
}

// ---------------------------------------------------------------------------
// K0b: x fp32 -> xb bf16 (same layout, for G=X X^T) AND xT bf16 (transposed,
// for V GEMM). 64x64 tiles.
// ---------------------------------------------------------------------------
__global__ __launch_bounds__(256) void xprep(const float* __restrict__ x,
                                             u16* __restrict__ xbb,
                                             u16* __restrict__ xT) {
    __shared__ float tile[64][65];
    int n0 = blockIdx.x * 64, c0 = blockIdx.y * 64, b = blockIdx.z;
    int t = threadIdx.x;
    int tx = t & 63, ty = t >> 6;   // ty 0..3
    const float* xsrc = x + (size_t)b * CDIM * NDIM;
    u16* xdst = xbb + (size_t)b * CDIM * NDIM;
#pragma unroll
    for (int j = 0; j < 16; j++) {
        size_t idx = (size_t)(c0 + ty + j * 4) * NDIM + n0 + tx;
        float v = xsrc[idx];
        tile[ty + j * 4][tx] = v;
        xdst[idx] = f2bf(v);
    }
    __syncthreads();
    u16* xTb = xT + (size_t)b * NDIM * CDIM;
    int r = t >> 3;          // 0..31
    int cg = (t & 7) * 8;
#pragma unroll
    for (int j = 0; j < 2; j++) {
        int rr = r + j * 32;
        u16 tmp[8];
#pragma unroll
        for (int i = 0; i < 8; i++) tmp[i] = f2bf(tile[cg + i][rr]);
        *(uint4*)(xTb + (size_t)(n0 + rr) * CDIM + c0 + cg) = *(uint4*)tmp;
    }
}

// ---------------------------------------------------------------------------
// K1: Gram of X, split-K=2. blockIdx.z = b*2+s; K window [s*2048,+2048).
// Stores TRANSPOSED: Gpart[s][b][j][i] = partial( X[i]·X[j] )  (float4 rows).
// ---------------------------------------------------------------------------
__global__ __launch_bounds__(256, 4) void gpart_mfma(const u16* __restrict__ xbb,
                                                     float* __restrict__ Gpart) {
    __shared__ __align__(16) u16 As[128 * BK];
    __shared__ __align__(16) u16 Bs[128 * BK];
    int bz = blockIdx.z;
    int b = bz >> 1, s = bz & 1;
    int m0 = blockIdx.y * 128, n0 = blockIdx.x * 128;
    const u16* Xb = xbb + (size_t)b * CDIM * NDIM + s * 2048;
    const u16* A = Xb + (size_t)m0 * NDIM;
    const u16* B = Xb + (size_t)n0 * NDIM;

    f32x4 acc[4][4];
#pragma unroll
    for (int i = 0; i < 4; i++)
#pragma unroll
        for (int j = 0; j < 4; j++) acc[i][j] = (f32x4){0.f, 0.f, 0.f, 0.f};

    gemm_core(A, B, NDIM, NDIM, 2048, As, Bs, acc);

    int wave = threadIdx.x >> 6, lane = threadIdx.x & 63;
    int wm = (wave & 1) * 64, wn = (wave >> 1) * 64;
    int lr = lane & 15, lq = lane >> 4;
    float* Gb = Gpart + (size_t)(s * BATCH + b) * CDIM * CDIM;
#pragma unroll
    for (int mt = 0; mt < 4; mt++)
#pragma unroll
        for (int nt = 0; nt < 4; nt++) {
            int i0 = m0 + wm + mt * 16 + lq * 4;   // i, 4 consecutive
            int j = n0 + wn + nt * 16 + lr;
            float4 v;
            v.x = acc[mt][nt][0]; v.y = acc[mt][nt][1];
            v.z = acc[mt][nt][2]; v.w = acc[mt][nt][3];
            *(float4*)(Gb + (size_t)j * CDIM + i0) = v;   // transposed store
        }
}

// ---------------------------------------------------------------------------
// K2: Gb[e] = bf16(Gpart0[e] + Gpart1[e]).  2M elems as float4.
// ---------------------------------------------------------------------------
__global__ __launch_bounds__(256) void greduce(const float* __restrict__ Gpart,
                                               u16* __restrict__ Gb) {
    int e = blockIdx.x * 256 + threadIdx.x;           // < 524288
    const float4* p0 = (const float4*)Gpart;
    const float4* p1 = p0 + (size_t)BATCH * CDIM * CDIM / 4;
    float4 a = p0[e], b = p1[e];
    ushort4 o;
    o.x = f2bf(a.x + b.x); o.y = f2bf(a.y + b.y);
    o.z = f2bf(a.z + b.z); o.w = f2bf(a.w + b.w);
    *(ushort4*)(Gb + (size_t)e * 4) = o;
}

// ---------------------------------------------------------------------------
// K3: V GEMM. C[o][n] = sum_c Wv[o][c] * xT[n][c]; store VT[b][n][o] bf16.
// ---------------------------------------------------------------------------
__global__ __launch_bounds__(256, 4) void vt_mfma(const u16* __restrict__ Wb,
                                                  const u16* __restrict__ xT,
                                                  u16* __restrict__ VT) {
    __shared__ __align__(16) u16 As[128 * BK];
    __shared__ __align__(16) u16 Bs[128 * BK];
    int b = blockIdx.z;
    int m0 = blockIdx.y * 128, n0 = blockIdx.x * 128;   // m=o (4 tiles), n (32 tiles)
    const u16* A = Wb + ((size_t)2 << 18) + (size_t)m0 * CDIM;
    const u16* B = xT + (size_t)b * NDIM * CDIM + (size_t)n0 * CDIM;

    f32x4 acc[4][4];
#pragma unroll
    for (int i = 0; i < 4; i++)
#pragma unroll
        for (int j = 0; j < 4; j++) acc[i][j] = (f32x4){0.f, 0.f, 0.f, 0.f};

    gemm_core(A, B, CDIM, CDIM, CDIM, As, Bs, acc);

    int wave = threadIdx.x >> 6, lane = threadIdx.x & 63;
    int wm = (wave & 1) * 64, wn = (wave >> 1) * 64;
    int lr = lane & 15, lq = lane >> 4;
    u16* O = VT + (size_t)b * NDIM * CDIM;
#pragma unroll
    for (int mt = 0; mt < 4; mt++)
#pragma unroll
        for (int nt = 0; nt < 4; nt++) {
            int r0 = m0 + wm + mt * 16 + lq * 4;   // o, 4 consecutive
            int cc = n0 + wn + nt * 16 + lr;        // n
            ushort4 pk;
            pk.x = f2bf(acc[mt][nt][0]); pk.y = f2bf(acc[mt][nt][1]);
            pk.z = f2bf(acc[mt][nt][2]); pk.w = f2bf(acc[mt][nt][3]);
            *(ushort4*)(O + (size_t)cc * CDIM + r0) = pk;
        }
}

// ---------------------------------------------------------------------------
// K4: Aq = Wq·G, Ak = Wk·G via G's stored transpose (NT):
// C[j][c] = sum_i Gb[j][i] * W[c][i]  ->  store A*[b][c][j] bf16 (j-contig).
// blockIdx.z = b*2 + which (0:q, 1:k).
// ---------------------------------------------------------------------------
__global__ __launch_bounds__(256, 4) void aqak_mfma(const u16* __restrict__ Gb,
                                                    const u16* __restrict__ Wb,
                                                    u16* __restrict__ Aqb,
                                                    u16* __restrict__ Akb) {
    __shared__ __align__(16) u16 As[128 * BK];
    __shared__ __align__(16) u16 Bs[128 * BK];
    int bz = blockIdx.z;
    int b = bz >> 1, which = bz & 1;
    int m0 = blockIdx.y * 128, n0 = blockIdx.x * 128;   // m=j, n=c
    const u16* A = Gb + (size_t)b * CDIM * CDIM + (size_t)m0 * CDIM;
    const u16* B = Wb + ((size_t)which << 18) + (size_t)n0 * CDIM;

    f32x4 acc[4][4];
#pragma unroll
    for (int i = 0; i < 4; i++)
#pragma unroll
        for (int j = 0; j < 4; j++) acc[i][j] = (f32x4){0.f, 0.f, 0.f, 0.f};

    gemm_core(A, B, CDIM, CDIM, CDIM, As, Bs, acc);

    int wave = threadIdx.x >> 6, lane = threadIdx.x & 63;
    int wm = (wave & 1) * 64, wn = (wave >> 1) * 64;
    int lr = lane & 15, lq = lane >> 4;
    u16* O = (which ? Akb : Aqb) + (size_t)b * CDIM * CDIM;
#pragma unroll
    for (int mt = 0; mt < 4; mt++)
#pragma unroll
        for (int nt = 0; nt < 4; nt++) {
            int r0 = m0 + wm + mt * 16 + lq * 4;   // j, 4 consecutive
            int cc = n0 + wn + nt * 16 + lr;        // c
            ushort4 pk;
            pk.x = f2bf(acc[mt][nt][0]); pk.y = f2bf(acc[mt][nt][1]);
            pk.z = f2bf(acc[mt][nt][2]); pk.w = f2bf(acc[mt][nt][3]);
            *(ushort4*)(O + (size_t)cc * CDIM + r0) = pk;
        }
}

// ---------------------------------------------------------------------------
// K5: rq[b][c] = rsqrt( sum_j Aq[b][c][j]*Wq[c][j] )  (= 1/||Q_c||), same for k.
// blockIdx.x = b*512+c, blockIdx.y = which.
// ---------------------------------------------------------------------------
__global__ __launch_bounds__(256) void nqnk(const u16* __restrict__ Aqb,
                                            const u16* __restrict__ Akb,
                                            const u16* __restrict__ Wb,
                                            float* __restrict__ rq,
                                            float* __restrict__ rk) {
    __shared__ float red[4];
    int row = blockIdx.x;            // b*512 + c
    int c = row & 511;
    int which = blockIdx.y;
    const u16* Ar = (which ? Akb : Aqb) + (size_t)row * CDIM;
    const u16* Wr = Wb + ((size_t)which << 18) + (size_t)c * CDIM;
    int t = threadIdx.x;
    float s = bf2f(Ar[t]) * bf2f(Wr[t]) + bf2f(Ar[t + 256]) * bf2f(Wr[t + 256]);
    for (int o = 32; o; o >>= 1) s += __shfl_down(s, o);
    if ((t & 63) == 0) red[t >> 6] = s;
    __syncthreads();
    if (t == 0) {
        float tot = red[0] + red[1] + red[2] + red[3];
        (which ? rk : rq)[row] = rsqrtf(tot);
    }
}

// ---------------------------------------------------------------------------
// K6: M_raw = Aq·Wk^T: C[c][d] = sum_j Aq[c][j]*Wk[d][j]; store T[b][d][c] fp32.
// ---------------------------------------------------------------------------
__global__ __launch_bounds__(256, 4) void qk_mfma(const u16* __restrict__ Aqb,
                                                  const u16* __restrict__ Wb,
                                                  float* __restrict__ T) {
    __shared__ __align__(16) u16 As[128 * BK];
    __shared__ __align__(16) u16 Bs[128 * BK];
    int b = blockIdx.z;
    int m0 = blockIdx.y * 128, n0 = blockIdx.x * 128;   // m=c, n=d
    const u16* A = Aqb + (size_t)b * CDIM * CDIM + (size_t)m0 * CDIM;
    const u16* B = Wb + ((size_t)1 << 18) + (size_t)n0 * CDIM;

    f32x4 acc[4][4];
#pragma unroll
    for (int i = 0; i < 4; i++)
#pragma unroll
        for (int j = 0; j < 4; j++) acc[i][j] = (f32x4){0.f, 0.f, 0.f, 0.f};

    gemm_core(A, B, CDIM, CDIM, CDIM, As, Bs, acc);

    int wave = threadIdx.x >> 6, lane = threadIdx.x & 63;
    int wm = (wave & 1) * 64, wn = (wave >> 1) * 64;
    int lr = lane & 15, lq = lane >> 4;
    float* Tb = T + (size_t)b * CDIM * CDIM;
#pragma unroll
    for (int mt = 0; mt < 4; mt++)
#pragma unroll
        for (int nt = 0; nt < 4; nt++) {
            int cbase = m0 + wm + mt * 16 + lq * 4;   // c, 4 consecutive
            int d = n0 + wn + nt * 16 + lr;
            float4 v;
            v.x = acc[mt][nt][0]; v.y = acc[mt][nt][1];
            v.z = acc[mt][nt][2]; v.w = acc[mt][nt][3];
            *(float4*)(Tb + (size_t)d * CDIM + cbase) = v;   // transposed store
        }
}

// ---------------------------------------------------------------------------
// K7: in-place per row of T (= column of S): v = raw*rq[c]*rk[d]; a=1-v;
// m=max(a)+eps; z=1-4a/m; softmax over c.
// ---------------------------------------------------------------------------
__global__ __launch_bounds__(256) void softmax_col(float* __restrict__ T,
                                                   const float* __restrict__ rq,
                                                   const float* __restrict__ rk) {
    __shared__ float red[4];
    int row = blockIdx.x;            // b*512 + d
    int b = row >> 9;
    float* p = T + (size_t)row * CDIM;
    int t = threadIdx.x;
    float rkd = rk[row];
    float q0 = rq[(b << 9) + t], q1 = rq[(b << 9) + t + 256];
    float v0 = p[t] * q0 * rkd;
    float v1 = p[t + 256] * q1 * rkd;
    float a0 = 1.f - v0, a1 = 1.f - v1;
    float m = fmaxf(a0, a1);
    for (int of = 32; of; of >>= 1) m = fmaxf(m, __shfl_down(m, of));
    if ((t & 63) == 0) red[t >> 6] = m;
    __syncthreads();
    m = fmaxf(fmaxf(red[0], red[1]), fmaxf(red[2], red[3])) + 1e-6f;
    __syncthreads();   // red about to be reused
    float inv = 4.f / m;   // /(m) then /0.25
    float b0 = 1.f - a0 * inv, b1 = 1.f - a1 * inv;
    float e0 = __expf(b0), e1 = __expf(b1);
    float s = e0 + e1;
    for (int of = 32; of; of >>= 1) s += __shfl_down(s, of);
    if ((t & 63) == 0) red[t >> 6] = s;
    __syncthreads();
    s = red[0] + red[1] + red[2] + red[3];
    float r = 1.f / s;
    p[t] = e0 * r;
    p[t + 256] = e1 * r;
}

// ---------------------------------------------------------------------------
// K8: rs_raw[b][c] += sum over 64-row d-chunk of Tf[b][d][c]  (atomic, d-split 8)
// ---------------------------------------------------------------------------
__global__ __launch_bounds__(256) void colsum(const float* __restrict__ T,
                                              float* __restrict__ rs_raw) {
    int b = blockIdx.x;
    int c = blockIdx.y * 256 + threadIdx.x;
    int d0 = blockIdx.z * 64;
    const float* p = T + (size_t)b * CDIM * CDIM + (size_t)d0 * CDIM + c;
    float s = 0.f;
    for (int d = 0; d < 64; d++) s += p[(size_t)d * CDIM];
    atomicAdd(&rs_raw[b * CDIM + c], s);
}

// ---------------------------------------------------------------------------
// K9: Mb[b][c][d] = bf16( Tf[b][d][c] / (rs_raw[b][c]+eps) )  (transpose+scale)
// ---------------------------------------------------------------------------
__global__ __launch_bounds__(256) void mscale(const float* __restrict__ T,
                                              const float* __restrict__ rs_raw,
                                              u16* __restrict__ Mb) {
    __shared__ float tile[32][33];
    int b = blockIdx.z;
    int d0 = blockIdx.x * 32, c0 = blockIdx.y * 32;
    int tx = threadIdx.x, ty = threadIdx.y;
    const float* Tb = T + (size_t)b * CDIM * CDIM;
#pragma unroll
    for (int j = 0; j < 4; j++)
        tile[ty + j * 8][tx] = Tb[(size_t)(d0 + ty + j * 8) * CDIM + c0 + tx];
    __syncthreads();
    const float* rsb = rs_raw + b * CDIM;
    u16* Mbb = Mb + (size_t)b * CDIM * CDIM;
#pragma unroll
    for (int j = 0; j < 4; j++) {
        int c = c0 + ty + j * 8;
        float inv = 1.f / (rsb[c] + 1e-6f);
        Mbb[(size_t)c * CDIM + d0 + tx] = f2bf(tile[tx][ty + j * 8] * inv);
    }
}

// ---------------------------------------------------------------------------
// K10: out[b][c][n] = x + gamma * sum_d Mb[c][d] * VT[n][d]
// ---------------------------------------------------------------------------
__global__ __launch_bounds__(256, 4) void out_mfma(const u16* __restrict__ Mb,
                                                   const u16* __restrict__ VT,
                                                   const float* __restrict__ x,
                                                   const float* __restrict__ gamma,
                                                   float* __restrict__ y) {
    __shared__ __align__(16) u16 As[128 * BK];
    __shared__ __align__(16) u16 Bs[128 * BK];
    int b = blockIdx.z;
    int m0 = blockIdx.y * 128, n0 = blockIdx.x * 128;
    const u16* A = Mb + (size_t)b * CDIM * CDIM + (size_t)m0 * CDIM;
    const u16* B = VT + (size_t)b * NDIM * CDIM + (size_t)n0 * CDIM;

    f32x4 acc[4][4];
#pragma unroll
    for (int i = 0; i < 4; i++)
#pragma unroll
        for (int j = 0; j < 4; j++) acc[i][j] = (f32x4){0.f, 0.f, 0.f, 0.f};

    gemm_core(A, B, CDIM, CDIM, CDIM, As, Bs, acc);

    int wave = threadIdx.x >> 6, lane = threadIdx.x & 63;
    int wm = (wave & 1) * 64, wn = (wave >> 1) * 64;
    int lr = lane & 15, lq = lane >> 4;
    float g = *gamma;
    const float* xb = x + (size_t)b * CDIM * NDIM;
    float* yb = y + (size_t)b * CDIM * NDIM;
#pragma unroll
    for (int mt = 0; mt < 4; mt++)
#pragma unroll
        for (int nt = 0; nt < 4; nt++) {
            int r0 = m0 + wm + mt * 16 + lq * 4;
            int cc = n0 + wn + nt * 16 + lr;
#pragma unroll
            for (int i = 0; i < 4; i++) {
                size_t idx = (size_t)(r0 + i) * NDIM + cc;
                yb[idx] = xb[idx] + g * acc[mt][nt][i];
            }
        }
}

// ---------------------------------------------------------------------------
extern "C" void kernel_launch(void* const* d_in, const int* in_sizes, int n_in,
                              void* d_out, int out_size, void* d_ws, size_t ws_size,
                              hipStream_t stream) {
    (void)in_sizes; (void)n_in; (void)out_size; (void)ws_size;
    const float* x     = (const float*)d_in[0];
    const float* Wq    = (const float*)d_in[1];
    const float* Wk    = (const float*)d_in[2];
    const float* Wv    = (const float*)d_in[3];
    const float* gamma = (const float*)d_in[4];
    float* y = (float*)d_out;

    char* ws = (char*)d_ws;
    // Aliases (lifetimes):
    //   xb [32,64M): dead after gpart -> VT (written by vt_mfma afterwards)
    //   Gpart [64,80M): dead after greduce -> T [64,72M) + Mb [72,76M)
    u16*   xT    = (u16*)(ws);                    // 32 MiB [B][4096][512] bf16
    u16*   xb    = (u16*)(ws + 33554432);         // 32 MiB [B][512][4096] bf16
    u16*   VT    = (u16*)(ws + 33554432);         // 32 MiB [B][4096][512] bf16 (alias xb)
    float* Gpart = (float*)(ws + 67108864);       // 16 MiB [2][B][512][512] fp32
    float* T     = (float*)(ws + 67108864);       //  8 MiB [B][512][512] fp32 (alias Gpart0)
    u16*   Mb    = (u16*)(ws + 75497472);         //  4 MiB [B][512][512] bf16 (alias Gpart1)
    u16*   Gb    = (u16*)(ws + 83886080);         //  4 MiB [B][512][512] bf16 (G transposed)
    u16*   Aqb   = (u16*)(ws + 88080384);         //  4 MiB [B][512][512] bf16
    u16*   Akb   = (u16*)(ws + 92274688);         //  4 MiB
    u16*   Wb    = (u16*)(ws + 96468992);         //  1.5 MiB [3][512][512] bf16
    float* rq    = (float*)(ws + 98041856);       // 16 KiB
    float* rk    = (float*)(ws + 98058240);       // 16 KiB
    float* rs_raw= (float*)(ws + 98074624);       // 16 KiB

    convw<<<3072, 256, 0, stream>>>(Wq, Wk, Wv, Wb, rs_raw);
    xprep<<<dim3(64, 8, 8), 256, 0, stream>>>(x, xb, xT);
    gpart_mfma<<<dim3(4, 4, 16), 256, 0, stream>>>(xb, Gpart);
    greduce<<<2048, 256, 0, stream>>>(Gpart, Gb);
    vt_mfma<<<dim3(32, 4, 8), 256, 0, stream>>>(Wb, xT, VT);     // overwrites xb region
    aqak_mfma<<<dim3(4, 4, 16), 256, 0, stream>>>(Gb, Wb, Aqb, Akb);
    nqnk<<<dim3(4096, 2), 256, 0, stream>>>(Aqb, Akb, Wb, rq, rk);
    qk_mfma<<<dim3(4, 4, 8), 256, 0, stream>>>(Aqb, Wb, T);      // overwrites Gpart0 region
    softmax_col<<<4096, 256, 0, stream>>>(T, rq, rk);
    colsum<<<dim3(8, 2, 8), 256, 0, stream>>>(T, rs_raw);
    mscale<<<dim3(16, 16, 8), dim3(32, 8), 0, stream>>>(T, rs_raw, Mb);
    out_mfma<<<dim3(32, 4, 8), 256, 0, stream>>>(Mb, VT, x, gamma, y);
}

// Round 6
// 276.836 us; speedup vs baseline: 1.3331x; 1.0181x over previous
//
#include <hip/hip_runtime.h>
#include <math.h>

// B=8, C=512, H=W=64, N=4096. All-fp32 inputs; bf16 MFMA compute internally.
// Algebraic form: M_raw = Wq (X X^T) Wk^T ; ||Q_c||^2 = diag(Wq G Wq^T).
typedef unsigned short u16;
typedef __attribute__((ext_vector_type(8))) short bf16x8;  // 8 bf16 = 4 VGPRs
typedef __attribute__((ext_vector_type(4))) float f32x4;

#define BATCH 8
#define CDIM 512
#define NDIM 4096
#define BK 32   // K-tile (bf16 elements); LDS rows are 64B, XOR-swizzled chunk slots

__device__ inline float bf2f(u16 u) {
    unsigned int x = ((unsigned int)u) << 16;
    return __uint_as_float(x);
}
__device__ inline u16 f2bf(float f) {  // round-to-nearest-even
    unsigned int u = __float_as_uint(f);
    unsigned int r = u + 0x7fffu + ((u >> 16) & 1u);
    return (u16)(r >> 16);
}

// async 16B/lane global->LDS DMA; LDS dest = uniform base + lane*16
#define GLOAD_LDS(g, l)                                                        \
    __builtin_amdgcn_global_load_lds(                                          \
        (const __attribute__((address_space(1))) void*)(g),                    \
        (__attribute__((address_space(3))) void*)(l), 16, 0, 0)

// ---------------------------------------------------------------------------
// Shared MFMA GEMM core (r4, proven): C[128x128] = A(m,k-contig) x B(n,k-contig)^T
// 256 threads = 4 waves 2x2; 4x4 grid of 16x16x32 MFMAs per wave.
// XOR bank swizzle with per-lane-constant offsets (VGPR=64, 0 conflicts):
//   staging chunk: (lane&3)^((lane>>3)&3);  fragment: lq^((lr>>1)&3).
// ---------------------------------------------------------------------------
__device__ inline void gemm_core(const u16* __restrict__ A, const u16* __restrict__ B,
                                 int lda, int ldb, int K,
                                 u16* As, u16* Bs, f32x4 (&acc)[4][4]) {
    const int t = threadIdx.x;
    const int wave = t >> 6, lane = t & 63;
    const int wm = (wave & 1) * 64, wn = (wave >> 1) * 64;
    const int lr = lane & 15, lq = lane >> 4;

    const int srow = wave * 32 + (lane >> 2);         // staging row (inst0); inst1 = +16
    const int sk = ((lane & 3) ^ ((lane >> 3) & 3)) * 8;  // swizzled source chunk
    const u16* Ap0 = A + (size_t)srow * lda + sk;
    const u16* Ap1 = Ap0 + (size_t)16 * lda;
    const u16* Bp0 = B + (size_t)srow * ldb + sk;
    const u16* Bp1 = Bp0 + (size_t)16 * ldb;
    u16* As0 = As + wave * 32 * BK;                   // wave-uniform LDS bases
    u16* As1 = As0 + 16 * BK;
    u16* Bs0 = Bs + wave * 32 * BK;
    u16* Bs1 = Bs0 + 16 * BK;

    const int fswz = (lq ^ ((lr >> 1) & 3)) * 8;
    const u16* Af = As + (wm + lr) * BK + fswz;
    const u16* Bf = Bs + (wn + lr) * BK + fswz;

    for (int k0 = 0; k0 < K; k0 += BK) {
        __syncthreads();
        GLOAD_LDS(Ap0 + k0, As0);
        GLOAD_LDS(Ap1 + k0, As1);
        GLOAD_LDS(Bp0 + k0, Bs0);
        GLOAD_LDS(Bp1 + k0, Bs1);
        __syncthreads();

        bf16x8 af[4], bfr[4];
#pragma unroll
        for (int i = 0; i < 4; i++) af[i] = *(const bf16x8*)(Af + i * 16 * BK);
#pragma unroll
        for (int i = 0; i < 4; i++) bfr[i] = *(const bf16x8*)(Bf + i * 16 * BK);
#pragma unroll
        for (int i = 0; i < 4; i++)
#pragma unroll
            for (int j = 0; j < 4; j++)
                acc[i][j] = __builtin_amdgcn_mfma_f32_16x16x32_bf16(af[i], bfr[j], acc[i][j], 0, 0, 0);
    }
}

// ---------------------------------------------------------------------------
// K0a: Wq/Wk/Wv fp32 -> bf16 into Wb[3][512][512]; blocks 0..47 zero the
// qss/kss/rs_raw accumulators (12288 contiguous floats).
// ---------------------------------------------------------------------------
__global__ __launch_bounds__(256) void convw(const float* __restrict__ Wq,
                                             const float* __restrict__ Wk,
                                             const float* __restrict__ Wv,
                                             u16* __restrict__ Wb,
                                             float* __restrict__ zacc) {
    int i = blockIdx.x * 256 + threadIdx.x;     // < 3*2^18
    if (blockIdx.x < 48) zacc[i] = 0.f;
    int w = i >> 18;
    int j = i & 262143;
    const float* s = (w == 0) ? Wq : (w == 1) ? Wk : Wv;
    Wb[i] = f2bf(s[j]);
}

// ---------------------------------------------------------------------------
// K0b: x fp32 -> xb bf16 (same layout, for G) AND xT bf16 (transposed, for V
// GEMM). 64x64 tiles, float4 loads / 8-16B stores.
// ---------------------------------------------------------------------------
__global__ __launch_bounds__(256) void xprep(const float* __restrict__ x,
                                             u16* __restrict__ xbb,
                                             u16* __restrict__ xT) {
    __shared__ __align__(16) float tile[64][68];
    int n0 = blockIdx.x * 64, c0 = blockIdx.y * 64, b = blockIdx.z;
    int t = threadIdx.x;
    int colg = (t & 15) * 4;     // float4 col within 64
    int rowg = t >> 4;           // 16 rows per pass
    const float* xsrc = x + (size_t)b * CDIM * NDIM;
    u16* xdst = xbb + (size_t)b * CDIM * NDIM;
#pragma unroll
    for (int j = 0; j < 4; j++) {
        int row = rowg + j * 16;
        size_t gidx = (size_t)(c0 + row) * NDIM + n0 + colg;
        float4 v = *(const float4*)(xsrc + gidx);
        ushort4 pk;
        pk.x = f2bf(v.x); pk.y = f2bf(v.y); pk.z = f2bf(v.z); pk.w = f2bf(v.w);
        *(ushort4*)(xdst + gidx) = pk;
        *(float4*)&tile[row][colg] = v;
    }
    __syncthreads();
    u16* xTb = xT + (size_t)b * NDIM * CDIM;
    int r = t >> 3;          // 0..31
    int cg = (t & 7) * 8;
#pragma unroll
    for (int j = 0; j < 2; j++) {
        int rr = r + j * 32;
        u16 tmp[8];
#pragma unroll
        for (int i = 0; i < 8; i++) tmp[i] = f2bf(tile[cg + i][rr]);
        *(uint4*)(xTb + (size_t)(n0 + rr) * CDIM + cg + c0) = *(uint4*)tmp;
    }
}

// ---------------------------------------------------------------------------
// K1: Gram of X, split-K=4 (512 blocks -> 2 blocks/CU for barrier overlap).
// blockIdx.z = b*4+s; K window [s*1024,+1024).
// Stores TRANSPOSED: Gpart[s][b][j][i] = partial( X[i]·X[j] ).
// ---------------------------------------------------------------------------
__global__ __launch_bounds__(256, 4) void gpart_mfma(const u16* __restrict__ xbb,
                                                     float* __restrict__ Gpart) {
    __shared__ __align__(16) u16 SMEM[2 * 128 * BK];
    u16* As = SMEM; u16* Bs = SMEM + 128 * BK;
    int bz = blockIdx.z;
    int b = bz >> 2, s = bz & 3;
    int m0 = blockIdx.y * 128, n0 = blockIdx.x * 128;
    const u16* Xb = xbb + (size_t)b * CDIM * NDIM + s * 1024;
    const u16* A = Xb + (size_t)m0 * NDIM;
    const u16* B = Xb + (size_t)n0 * NDIM;

    f32x4 acc[4][4];
#pragma unroll
    for (int i = 0; i < 4; i++)
#pragma unroll
        for (int j = 0; j < 4; j++) acc[i][j] = (f32x4){0.f, 0.f, 0.f, 0.f};

    gemm_core(A, B, NDIM, NDIM, 1024, As, Bs, acc);

    int wave = threadIdx.x >> 6, lane = threadIdx.x & 63;
    int wm = (wave & 1) * 64, wn = (wave >> 1) * 64;
    int lr = lane & 15, lq = lane >> 4;
    float* Gb = Gpart + (size_t)(s * BATCH + b) * CDIM * CDIM;
#pragma unroll
    for (int mt = 0; mt < 4; mt++)
#pragma unroll
        for (int nt = 0; nt < 4; nt++) {
            int i0 = m0 + wm + mt * 16 + lq * 4;   // i, 4 consecutive
            int j = n0 + wn + nt * 16 + lr;
            float4 v;
            v.x = acc[mt][nt][0]; v.y = acc[mt][nt][1];
            v.z = acc[mt][nt][2]; v.w = acc[mt][nt][3];
            *(float4*)(Gb + (size_t)j * CDIM + i0) = v;   // transposed store
        }
}

// ---------------------------------------------------------------------------
// K2: Gb[e] = bf16( sum of 4 split partials ).
// ---------------------------------------------------------------------------
__global__ __launch_bounds__(256) void greduce(const float* __restrict__ Gpart,
                                               u16* __restrict__ Gb) {
    int e = blockIdx.x * 256 + threadIdx.x;           // < 524288
    const size_t S = (size_t)BATCH * CDIM * CDIM / 4;
    const float4* p = (const float4*)Gpart;
    float4 a = p[e], b = p[e + S], c = p[e + 2 * S], d = p[e + 3 * S];
    ushort4 o;
    o.x = f2bf(a.x + b.x + c.x + d.x); o.y = f2bf(a.y + b.y + c.y + d.y);
    o.z = f2bf(a.z + b.z + c.z + d.z); o.w = f2bf(a.w + b.w + c.w + d.w);
    *(ushort4*)(Gb + (size_t)e * 4) = o;
}

// ---------------------------------------------------------------------------
// K3: V GEMM. C[o][n] = sum_c Wv[o][c]*xT[n][c]; store VT[b][n][o] bf16.
// Epilogue: LDS transpose (per-wave 64n x 16o bf16, stride 24) -> 16B stores
// contiguous in o (vs 8B scattered before).
// ---------------------------------------------------------------------------
__global__ __launch_bounds__(256, 4) void vt_mfma(const u16* __restrict__ Wb,
                                                  const u16* __restrict__ xT,
                                                  u16* __restrict__ VT) {
    __shared__ __align__(16) u16 SMEM[2 * 128 * BK];
    u16* As = SMEM; u16* Bs = SMEM + 128 * BK;
    int b = blockIdx.z;
    int m0 = blockIdx.y * 128, n0 = blockIdx.x * 128;   // m=o, n
    const u16* A = Wb + ((size_t)2 << 18) + (size_t)m0 * CDIM;
    const u16* B = xT + (size_t)b * NDIM * CDIM + (size_t)n0 * CDIM;

    f32x4 acc[4][4];
#pragma unroll
    for (int i = 0; i < 4; i++)
#pragma unroll
        for (int j = 0; j < 4; j++) acc[i][j] = (f32x4){0.f, 0.f, 0.f, 0.f};

    gemm_core(A, B, CDIM, CDIM, CDIM, As, Bs, acc);

    int wave = threadIdx.x >> 6, lane = threadIdx.x & 63;
    int wm = (wave & 1) * 64, wn = (wave >> 1) * 64;
    int lr = lane & 15, lq = lane >> 4;
    u16* O = VT + (size_t)b * NDIM * CDIM;
    u16* wl = SMEM + wave * 1536;          // 64 x 24 u16 per wave (3 KB)
    __syncthreads();                        // staging buffers now dead
#pragma unroll
    for (int mt = 0; mt < 4; mt++) {
#pragma unroll
        for (int nt = 0; nt < 4; nt++) {
            ushort4 pk;
            pk.x = f2bf(acc[mt][nt][0]); pk.y = f2bf(acc[mt][nt][1]);
            pk.z = f2bf(acc[mt][nt][2]); pk.w = f2bf(acc[mt][nt][3]);
            *(ushort4*)(wl + (nt * 16 + lr) * 24 + lq * 4) = pk;
        }
        __syncthreads();
        int obase = m0 + wm + mt * 16;
        size_t cc = (size_t)(n0 + wn + lane) * CDIM + obase;
#pragma unroll
        for (int h = 0; h < 2; h++)
            *(uint4*)(O + cc + h * 8) = *(const uint4*)(wl + lane * 24 + h * 8);
        __syncthreads();
    }
}

// ---------------------------------------------------------------------------
// K4: which=0: Aq = Wq·G (store, c-major/j-contig) + diag dots -> qss atomics.
//     which=1: Ak·Wk diag dots only -> kss atomics (Ak never materialized).
// C[j][c] = sum_i Gb[j][i]*W[c][i] via G's stored transpose (NT).
// blockIdx.z = b*2 + which.
// ---------------------------------------------------------------------------
__global__ __launch_bounds__(256, 4) void aqak_mfma(const u16* __restrict__ Gb,
                                                    const u16* __restrict__ Wb,
                                                    u16* __restrict__ Aqb,
                                                    float* __restrict__ qss,
                                                    float* __restrict__ kss) {
    __shared__ __align__(16) u16 SMEM[2 * 128 * BK];
    u16* As = SMEM; u16* Bs = SMEM + 128 * BK;
    int bz = blockIdx.z;
    int b = bz >> 1, which = bz & 1;
    int m0 = blockIdx.y * 128, n0 = blockIdx.x * 128;   // m=j, n=c
    const u16* A = Gb + (size_t)b * CDIM * CDIM + (size_t)m0 * CDIM;
    const u16* Wm = Wb + ((size_t)which << 18);
    const u16* B = Wm + (size_t)n0 * CDIM;

    f32x4 acc[4][4];
#pragma unroll
    for (int i = 0; i < 4; i++)
#pragma unroll
        for (int j = 0; j < 4; j++) acc[i][j] = (f32x4){0.f, 0.f, 0.f, 0.f};

    gemm_core(A, B, CDIM, CDIM, CDIM, As, Bs, acc);

    int wave = threadIdx.x >> 6, lane = threadIdx.x & 63;
    int wm = (wave & 1) * 64, wn = (wave >> 1) * 64;
    int lr = lane & 15, lq = lane >> 4;

    if (which == 0) {
        u16* O = Aqb + (size_t)b * CDIM * CDIM;
#pragma unroll
        for (int mt = 0; mt < 4; mt++)
#pragma unroll
            for (int nt = 0; nt < 4; nt++) {
                int r0 = m0 + wm + mt * 16 + lq * 4;   // j
                int cc = n0 + wn + nt * 16 + lr;        // c
                ushort4 pk;
                pk.x = f2bf(acc[mt][nt][0]); pk.y = f2bf(acc[mt][nt][1]);
                pk.z = f2bf(acc[mt][nt][2]); pk.w = f2bf(acc[mt][nt][3]);
                *(ushort4*)(O + (size_t)cc * CDIM + r0) = pk;
            }
    }
    // fused diag dot: ss[c] += sum_{j in block m-range} C[j][c] * W[c][j]
    float* ss = (which ? kss : qss) + (b << 9);
#pragma unroll
    for (int nt = 0; nt < 4; nt++) {
        int cc = n0 + wn + nt * 16 + lr;
        float s = 0.f;
#pragma unroll
        for (int mt = 0; mt < 4; mt++) {
            int j0 = m0 + wm + mt * 16 + lq * 4;
            ushort4 wv = *(const ushort4*)(Wm + (size_t)cc * CDIM + j0);
            s += acc[mt][nt][0] * bf2f(wv.x) + acc[mt][nt][1] * bf2f(wv.y)
               + acc[mt][nt][2] * bf2f(wv.z) + acc[mt][nt][3] * bf2f(wv.w);
        }
        s += __shfl_xor(s, 16); s += __shfl_xor(s, 32);
        if (lq == 0) atomicAdd(&ss[cc], s);
    }
}

// ---------------------------------------------------------------------------
// K5: M_raw = Aq·Wk^T, split-K=2. blockIdx.z = b*2+s; K window [s*256,+256).
// Tpart[s][b][d][c] = partial( sum_j Aq[c][j]*Wk[d][j] ), raw fp32.
// ---------------------------------------------------------------------------
__global__ __launch_bounds__(256, 4) void qk_part(const u16* __restrict__ Aqb,
                                                  const u16* __restrict__ Wb,
                                                  float* __restrict__ Tpart) {
    __shared__ __align__(16) u16 SMEM[2 * 128 * BK];
    u16* As = SMEM; u16* Bs = SMEM + 128 * BK;
    int bz = blockIdx.z;
    int b = bz >> 1, s = bz & 1;
    int m0 = blockIdx.y * 128, n0 = blockIdx.x * 128;   // m=c, n=d
    const u16* A = Aqb + (size_t)b * CDIM * CDIM + (size_t)m0 * CDIM + s * 256;
    const u16* B = Wb + ((size_t)1 << 18) + (size_t)n0 * CDIM + s * 256;

    f32x4 acc[4][4];
#pragma unroll
    for (int i = 0; i < 4; i++)
#pragma unroll
        for (int j = 0; j < 4; j++) acc[i][j] = (f32x4){0.f, 0.f, 0.f, 0.f};

    gemm_core(A, B, CDIM, CDIM, 256, As, Bs, acc);

    int wave = threadIdx.x >> 6, lane = threadIdx.x & 63;
    int wm = (wave & 1) * 64, wn = (wave >> 1) * 64;
    int lr = lane & 15, lq = lane >> 4;
    float* Tb = Tpart + (size_t)(s * BATCH + b) * CDIM * CDIM;
#pragma unroll
    for (int mt = 0; mt < 4; mt++)
#pragma unroll
        for (int nt = 0; nt < 4; nt++) {
            int cbase = m0 + wm + mt * 16 + lq * 4;   // c
            int d = n0 + wn + nt * 16 + lr;
            float4 v;
            v.x = acc[mt][nt][0]; v.y = acc[mt][nt][1];
            v.z = acc[mt][nt][2]; v.w = acc[mt][nt][3];
            *(float4*)(Tb + (size_t)d * CDIM + cbase) = v;
        }
}

// ---------------------------------------------------------------------------
// K6: fused split reduce + cosine scale (rsqrt of diag sums) + column softmax.
// Row (b,d): v[c] = (T0+T1)*rsqrt(qss[c])*rsqrt(kss[d]); a=1-v; m=max+eps;
// z=1-4a/m; softmax over c. Writes Tf.
// ---------------------------------------------------------------------------
__global__ __launch_bounds__(256) void softmax_col(const float* __restrict__ Tpart,
                                                   const float* __restrict__ qss,
                                                   const float* __restrict__ kss,
                                                   float* __restrict__ Tf) {
    __shared__ float red[4];
    int row = blockIdx.x;            // b*512 + d
    int b = row >> 9;
    const float* p = Tpart + (size_t)row * CDIM;
    float* o = Tf + (size_t)row * CDIM;
    int t = threadIdx.x;
    const size_t SS = (size_t)BATCH * CDIM * CDIM;
    float rkd = rsqrtf(kss[row]);
    float q0 = rsqrtf(qss[(b << 9) + t]), q1 = rsqrtf(qss[(b << 9) + t + 256]);
    float v0 = (p[t] + p[t + SS]) * q0 * rkd;
    float v1 = (p[t + 256] + p[t + 256 + SS]) * q1 * rkd;
    float a0 = 1.f - v0, a1 = 1.f - v1;
    float m = fmaxf(a0, a1);
    for (int of = 32; of; of >>= 1) m = fmaxf(m, __shfl_down(m, of));
    if ((t & 63) == 0) red[t >> 6] = m;
    __syncthreads();
    m = fmaxf(fmaxf(red[0], red[1]), fmaxf(red[2], red[3])) + 1e-6f;
    __syncthreads();
    float inv = 4.f / m;
    float b0 = 1.f - a0 * inv, b1 = 1.f - a1 * inv;
    float e0 = __expf(b0), e1 = __expf(b1);
    float s = e0 + e1;
    for (int of = 32; of; of >>= 1) s += __shfl_down(s, of);
    if ((t & 63) == 0) red[t >> 6] = s;
    __syncthreads();
    s = red[0] + red[1] + red[2] + red[3];
    float r = 1.f / s;
    o[t] = e0 * r;
    o[t + 256] = e1 * r;
}

// ---------------------------------------------------------------------------
// K7: rs_raw[b][c] += sum over 64-row d-chunk of Tf[b][d][c]
// ---------------------------------------------------------------------------
__global__ __launch_bounds__(256) void colsum(const float* __restrict__ T,
                                              float* __restrict__ rs_raw) {
    int b = blockIdx.x;
    int c = blockIdx.y * 256 + threadIdx.x;
    int d0 = blockIdx.z * 64;
    const float* p = T + (size_t)b * CDIM * CDIM + (size_t)d0 * CDIM + c;
    float s = 0.f;
    for (int d = 0; d < 64; d++) s += p[(size_t)d * CDIM];
    atomicAdd(&rs_raw[b * CDIM + c], s);
}

// ---------------------------------------------------------------------------
// K8: Mb[b][c][d] = bf16( Tf[b][d][c] / (rs_raw[b][c]+eps) )
// ---------------------------------------------------------------------------
__global__ __launch_bounds__(256) void mscale(const float* __restrict__ T,
                                              const float* __restrict__ rs_raw,
                                              u16* __restrict__ Mb) {
    __shared__ float tile[32][33];
    int b = blockIdx.z;
    int d0 = blockIdx.x * 32, c0 = blockIdx.y * 32;
    int tx = threadIdx.x, ty = threadIdx.y;
    const float* Tb = T + (size_t)b * CDIM * CDIM;
#pragma unroll
    for (int j = 0; j < 4; j++)
        tile[ty + j * 8][tx] = Tb[(size_t)(d0 + ty + j * 8) * CDIM + c0 + tx];
    __syncthreads();
    const float* rsb = rs_raw + b * CDIM;
    u16* Mbb = Mb + (size_t)b * CDIM * CDIM;
#pragma unroll
    for (int j = 0; j < 4; j++) {
        int c = c0 + ty + j * 8;
        float inv = 1.f / (rsb[c] + 1e-6f);
        Mbb[(size_t)c * CDIM + d0 + tx] = f2bf(tile[tx][ty + j * 8] * inv);
    }
}

// ---------------------------------------------------------------------------
// K9: out[b][c][n] = x + gamma * sum_d Mb[c][d]*VT[n][d].
// Epilogue: per-wave 16x64 fp32 LDS transpose (stride 68) -> float4 x-loads
// and y-stores (16B/lane) instead of 4B scalars.
// ---------------------------------------------------------------------------
__global__ __launch_bounds__(256, 4) void out_mfma(const u16* __restrict__ Mb,
                                                   const u16* __restrict__ VT,
                                                   const float* __restrict__ x,
                                                   const float* __restrict__ gamma,
                                                   float* __restrict__ y) {
    __shared__ __align__(16) u16 SMEM[2 * 128 * BK + 512];   // 17408 B for epilogue
    u16* As = SMEM; u16* Bs = SMEM + 128 * BK;
    int b = blockIdx.z;
    int m0 = blockIdx.y * 128, n0 = blockIdx.x * 128;
    const u16* A = Mb + (size_t)b * CDIM * CDIM + (size_t)m0 * CDIM;
    const u16* B = VT + (size_t)b * NDIM * CDIM + (size_t)n0 * CDIM;

    f32x4 acc[4][4];
#pragma unroll
    for (int i = 0; i < 4; i++)
#pragma unroll
        for (int j = 0; j < 4; j++) acc[i][j] = (f32x4){0.f, 0.f, 0.f, 0.f};

    gemm_core(A, B, CDIM, CDIM, CDIM, As, Bs, acc);

    int wave = threadIdx.x >> 6, lane = threadIdx.x & 63;
    int wm = (wave & 1) * 64, wn = (wave >> 1) * 64;
    int lr = lane & 15, lq = lane >> 4;
    float g = *gamma;
    const float* xbase = x + (size_t)b * CDIM * NDIM;
    float* ybase = y + (size_t)b * CDIM * NDIM;
    float* wl = (float*)SMEM + wave * 1088;   // 16 x 68 fp32 per wave
    __syncthreads();                           // staging buffers now dead
#pragma unroll
    for (int mt = 0; mt < 4; mt++) {
#pragma unroll
        for (int nt = 0; nt < 4; nt++)
#pragma unroll
            for (int i = 0; i < 4; i++)
                wl[(lq * 4 + i) * 68 + nt * 16 + lr] = acc[mt][nt][i];
        __syncthreads();
#pragma unroll
        for (int rr = 0; rr < 4; rr++) {
            int lrow = rr * 4 + lq;
            float4 v = *(const float4*)(wl + lrow * 68 + lr * 4);
            size_t idx = (size_t)(m0 + wm + mt * 16 + lrow) * NDIM + n0 + wn + lr * 4;
            float4 xv = *(const float4*)(xbase + idx);
            float4 o4;
            o4.x = xv.x + g * v.x; o4.y = xv.y + g * v.y;
            o4.z = xv.z + g * v.z; o4.w = xv.w + g * v.w;
            *(float4*)(ybase + idx) = o4;
        }
        __syncthreads();
    }
}

// ---------------------------------------------------------------------------
extern "C" void kernel_launch(void* const* d_in, const int* in_sizes, int n_in,
                              void* d_out, int out_size, void* d_ws, size_t ws_size,
                              hipStream_t stream) {
    (void)in_sizes; (void)n_in; (void)out_size; (void)ws_size;
    const float* x     = (const float*)d_in[0];
    const float* Wq    = (const float*)d_in[1];
    const float* Wk    = (const float*)d_in[2];
    const float* Wv    = (const float*)d_in[3];
    const float* gamma = (const float*)d_in[4];
    float* y = (float*)d_out;

    char* ws = (char*)d_ws;
    // Lifetimes: xb dead after gpart -> VT overwrites it (vt runs after).
    // Gpart dead after greduce -> Tpart (qk), Tf (softmax), Mb (mscale) alias it.
    u16*   xT    = (u16*)(ws);                    // 32 MiB [B][4096][512] bf16
    u16*   xb    = (u16*)(ws + 33554432);         // 32 MiB [B][512][4096] bf16
    u16*   VT    = (u16*)(ws + 33554432);         // 32 MiB (alias xb)
    float* Gpart = (float*)(ws + 67108864);       // 32 MiB [4][B][512][512] fp32
    float* Tpart = (float*)(ws + 67108864);       // 16 MiB [2][B][512][512] (alias)
    float* Tf    = (float*)(ws + 83886080);       //  8 MiB (alias Gpart[2])
    u16*   Mb    = (u16*)(ws + 92274688);         //  4 MiB (alias Gpart[3])
    u16*   Gb    = (u16*)(ws + 100663296);        //  4 MiB bf16 (G transposed)
    u16*   Aqb   = (u16*)(ws + 104857600);        //  4 MiB bf16
    u16*   Wb    = (u16*)(ws + 109051904);        //  1.5 MiB [3][512][512] bf16
    float* qss   = (float*)(ws + 110624768);      // 16 KiB  ||Q_c||^2
    float* kss   = (float*)(ws + 110641152);      // 16 KiB  ||K_d||^2
    float* rs_raw= (float*)(ws + 110657536);      // 16 KiB  col sums of Tf

    convw<<<3072, 256, 0, stream>>>(Wq, Wk, Wv, Wb, qss);  // qss/kss/rs_raw zeroed
    xprep<<<dim3(64, 8, 8), 256, 0, stream>>>(x, xb, xT);
    gpart_mfma<<<dim3(4, 4, 32), 256, 0, stream>>>(xb, Gpart);
    greduce<<<2048, 256, 0, stream>>>(Gpart, Gb);
    vt_mfma<<<dim3(32, 4, 8), 256, 0, stream>>>(Wb, xT, VT);      // overwrites xb
    aqak_mfma<<<dim3(4, 4, 16), 256, 0, stream>>>(Gb, Wb, Aqb, qss, kss);
    qk_part<<<dim3(4, 4, 16), 256, 0, stream>>>(Aqb, Wb, Tpart);  // overwrites Gpart[0:2]
    softmax_col<<<4096, 256, 0, stream>>>(Tpart, qss, kss, Tf);
    colsum<<<dim3(8, 2, 8), 256, 0, stream>>>(Tf, rs_raw);
    mscale<<<dim3(16, 16, 8), dim3(32, 8), 0, stream>>>(Tf, rs_raw, Mb);
    out_mfma<<<dim3(32, 4, 8), 256, 0, stream>>>(Mb, VT, x, gamma, y);
}